// Round 3
// baseline (412.689 us; speedup 1.0000x reference)
//
#include <hip/hip_runtime.h>

// PoolingRetriever collapses: softmax over a size-1 axis == 1.0, so
//   out = (x @ Wv.T + bv) @ Wo.T + bo
// x: (65536,768) f32. Wv: (64,768). Wo: (768,64). out: (65536,768) f32.
//
// Latency-bound fix (round 3): 16 rows/wave -> 4096 waves (16/CU), plus an
// explicit deep pipeline (4 kc of x + 2 kc of weight frags in flight per
// wave). Weights pre-packed to bf16 MFMA B-fragment order in d_ws (L2-hot).
// Kernel is barrier-free; V transpose is wave-private LDS. Non-temporal
// loads for x / stores for out keep L2 free for weight fragments.

#define DIM 768
#define NB  64
#define KC  (DIM / 32)          // 24 k-chunks of 32
#define RPW 16                  // rows per wave
#define WPB 4                   // waves per block (256 threads)
#define RPB (RPW * WPB)         // 64 rows per block
#define WV_ELEMS (NB * DIM)     // 49152 per weight matrix

typedef __attribute__((ext_vector_type(8))) short short8;
typedef __attribute__((ext_vector_type(4))) float f32x4;

__device__ __forceinline__ unsigned short f2bf(float f) {
    union { float f; unsigned int u; } v; v.f = f;
    return (unsigned short)((v.u + 0x7fffu + ((v.u >> 16) & 1u)) >> 16);
}

__device__ __forceinline__ short8 pack_bf8(f32x4 lo, f32x4 hi) {
    short8 r;
    r[0] = (short)f2bf(lo[0]); r[1] = (short)f2bf(lo[1]);
    r[2] = (short)f2bf(lo[2]); r[3] = (short)f2bf(lo[3]);
    r[4] = (short)f2bf(hi[0]); r[5] = (short)f2bf(hi[1]);
    r[6] = (short)f2bf(hi[2]); r[7] = (short)f2bf(hi[3]);
    return r;
}

__device__ __forceinline__ f32x4 ld_nt_f4(const float* p) {
    return __builtin_nontemporal_load((const f32x4*)p);
}

// Pack Wv and Wo (f32, row-major) into bf16 MFMA B-fragment order.
// pWv frag (kc,t): ((kc*4+t)*64 + lane)*8 + j  = Wv[t*16+(lane&15)][kc*32+(lane>>4)*8+j]
// pWo frag (tile,h): ((tile*2+h)*64 + lane)*8 + j = Wo[tile*16+(lane&15)][h*32+(lane>>4)*8+j]
__global__ void pack_weights(const float* __restrict__ Wv, const float* __restrict__ Wo,
                             unsigned short* __restrict__ pWv, unsigned short* __restrict__ pWo) {
    int e = blockIdx.x * 256 + threadIdx.x;      // 0 .. 2*49152-1
    int which = (e >= WV_ELEMS) ? 1 : 0;
    int idx = which ? e - WV_ELEMS : e;
    int frag = idx >> 9;
    int lane = (idx >> 3) & 63;
    int j = idx & 7;
    int lm = lane & 15, lq = lane >> 4;
    float v;
    if (!which) {
        int kc = frag >> 2, t = frag & 3;
        v = Wv[(t * 16 + lm) * DIM + kc * 32 + lq * 8 + j];
    } else {
        int tile = frag >> 1, h = frag & 1;
        v = Wo[(tile * 16 + lm) * NB + h * 32 + lq * 8 + j];
    }
    (which ? pWo : pWv)[idx] = f2bf(v);
}

__global__ __launch_bounds__(256, 4)
void pr_main(const float* __restrict__ x,
             const unsigned short* __restrict__ pWv, const float* __restrict__ bv,
             const unsigned short* __restrict__ pWo, const float* __restrict__ bo,
             float* __restrict__ out)
{
    __shared__ unsigned short sV[WPB][RPW][72];   // 4*16*72*2 = 9216 B

    const int tid  = threadIdx.x;
    const int wave = tid >> 6;
    const int lane = tid & 63;
    const int lq   = lane >> 4;
    const int lm   = lane & 15;
    const long row0 = (long)blockIdx.x * RPB + wave * RPW;

    // ---------------- Phase 1: V = x @ Wv.T (per wave: 16 rows x 64 n) ----
    f32x4 accV[4];
    #pragma unroll
    for (int t = 0; t < 4; ++t) accV[t] = (f32x4){0.f, 0.f, 0.f, 0.f};

    const float* xp = x + (row0 + lm) * DIM + lq * 8;
    const short8* wv = (const short8*)pWv + lane;   // + frag*64

    // rolling pipeline buffers: 4 kc of x (32 VGPR), 2 kc of B (32 VGPR)
    f32x4 aP[4][2];
    short8 bP[2][4];
    #pragma unroll
    for (int i = 0; i < 4; ++i) {
        aP[i][0] = ld_nt_f4(xp + i * 32);
        aP[i][1] = ld_nt_f4(xp + i * 32 + 4);
    }
    #pragma unroll
    for (int i = 0; i < 2; ++i)
        #pragma unroll
        for (int t = 0; t < 4; ++t) bP[i][t] = wv[(i * 4 + t) * 64];

    #pragma unroll
    for (int kc = 0; kc < KC; ++kc) {
        const int sA = kc & 3, sB = kc & 1;
        const f32x4 a_lo = aP[sA][0];
        const f32x4 a_hi = aP[sA][1];
        short8 b0 = bP[sB][0], b1 = bP[sB][1], b2 = bP[sB][2], b3 = bP[sB][3];
        if (kc + 4 < KC) {
            aP[sA][0] = ld_nt_f4(xp + (kc + 4) * 32);
            aP[sA][1] = ld_nt_f4(xp + (kc + 4) * 32 + 4);
        }
        if (kc + 2 < KC) {
            #pragma unroll
            for (int t = 0; t < 4; ++t) bP[sB][t] = wv[((kc + 2) * 4 + t) * 64];
        }
        const short8 a = pack_bf8(a_lo, a_hi);
        accV[0] = __builtin_amdgcn_mfma_f32_16x16x32_bf16(a, b0, accV[0], 0, 0, 0);
        accV[1] = __builtin_amdgcn_mfma_f32_16x16x32_bf16(a, b1, accV[1], 0, 0, 0);
        accV[2] = __builtin_amdgcn_mfma_f32_16x16x32_bf16(a, b2, accV[2], 0, 0, 0);
        accV[3] = __builtin_amdgcn_mfma_f32_16x16x32_bf16(a, b3, accV[3], 0, 0, 0);
    }

    // ------- Phase 1.5: V + bv -> LDS (bf16), C-layout -> A-layout --------
    // Wave-private (sV[wave]): no __syncthreads needed, lgkmcnt orders it.
    #pragma unroll
    for (int t = 0; t < 4; ++t) {
        const float bvn = bv[t * 16 + lm];
        #pragma unroll
        for (int r = 0; r < 4; ++r) {
            sV[wave][lq * 4 + r][t * 16 + lm] = f2bf(accV[t][r] + bvn);
        }
    }
    short8 aV0 = *(const short8*)&sV[wave][lm][lq * 8];
    short8 aV1 = *(const short8*)&sV[wave][lm][32 + lq * 8];

    // ---------------- Phase 2: out = V @ Wo.T + bo ------------------------
    const short8* wo = (const short8*)pWo + lane;   // + frag*64

    short8 woP[2][8];   // 2-deep prefetch of 8 frags/cc
    #pragma unroll
    for (int i = 0; i < 2; ++i)
        #pragma unroll
        for (int t = 0; t < 4; ++t) {
            woP[i][t * 2 + 0] = wo[((i * 4 + t) * 2 + 0) * 64];
            woP[i][t * 2 + 1] = wo[((i * 4 + t) * 2 + 1) * 64];
        }

    #pragma unroll
    for (int cc = 0; cc < 12; ++cc) {
        const int s = cc & 1;
        f32x4 acc[4];
        #pragma unroll
        for (int t = 0; t < 4; ++t) acc[t] = (f32x4){0.f, 0.f, 0.f, 0.f};

        short8 cur[8];
        #pragma unroll
        for (int i = 0; i < 8; ++i) cur[i] = woP[s][i];

        if (cc + 2 < 12) {
            #pragma unroll
            for (int t = 0; t < 4; ++t) {
                woP[s][t * 2 + 0] = wo[(((cc + 2) * 4 + t) * 2 + 0) * 64];
                woP[s][t * 2 + 1] = wo[(((cc + 2) * 4 + t) * 2 + 1) * 64];
            }
        }

        #pragma unroll
        for (int t = 0; t < 4; ++t) {
            acc[t] = __builtin_amdgcn_mfma_f32_16x16x32_bf16(aV0, cur[t * 2 + 0], acc[t], 0, 0, 0);
            acc[t] = __builtin_amdgcn_mfma_f32_16x16x32_bf16(aV1, cur[t * 2 + 1], acc[t], 0, 0, 0);
        }

        #pragma unroll
        for (int t = 0; t < 4; ++t) {
            const int col = cc * 64 + t * 16 + lm;
            const float boc = bo[col];
            #pragma unroll
            for (int r = 0; r < 4; ++r) {
                __builtin_nontemporal_store(acc[t][r] + boc,
                    out + (row0 + lq * 4 + r) * DIM + col);
            }
        }
    }
}

extern "C" void kernel_launch(void* const* d_in, const int* in_sizes, int n_in,
                              void* d_out, int out_size, void* d_ws, size_t ws_size,
                              hipStream_t stream) {
    const float* x  = (const float*)d_in[0];
    // d_in[1..5] = q_state, Wq, bq, Wk, bk — mathematically dead: softmax over
    // the size-1 sequence axis is identically 1, so out depends only on v path.
    const float* Wv = (const float*)d_in[6];
    const float* bv = (const float*)d_in[7];
    const float* Wo = (const float*)d_in[8];
    const float* bo = (const float*)d_in[9];
    float* out = (float*)d_out;

    unsigned short* pWv = (unsigned short*)d_ws;          // 96 KB
    unsigned short* pWo = pWv + WV_ELEMS;                 // 96 KB

    pack_weights<<<dim3(2 * WV_ELEMS / 256), dim3(256), 0, stream>>>(Wv, Wo, pWv, pWo);

    const int Bn = in_sizes[0] / DIM;                     // 65536
    pr_main<<<dim3(Bn / RPB), dim3(256), 0, stream>>>(x, pWv, bv, pWo, bo, out);
}